// Round 21
// baseline (183.475 us; speedup 1.0000x reference)
//
#include <hip/hip_runtime.h>

typedef __attribute__((ext_vector_type(8))) short short8;
typedef __attribute__((ext_vector_type(4))) float f32x4;
typedef unsigned short u16;
typedef __attribute__((ext_vector_type(4))) unsigned short u16x4;

#define S_LEN 2048
#define DMODEL 1024
#define NH 16
#define HD 64

static __device__ __forceinline__ u16 f2bf(float f) {
    union { float f; unsigned u; } x; x.f = f;
    unsigned r = x.u + 0x7fffu + ((x.u >> 16) & 1u);
    return (u16)(r >> 16);
}

static __device__ __forceinline__ float bf2f(u16 v) {
    union { unsigned u; float f; } x; x.u = ((unsigned)v) << 16;
    return x.f;
}

// pack two f32 -> one u32 of two bf16 (RNE), src0 -> low 16, src1 -> high 16
static __device__ __forceinline__ unsigned cvtpk_bf16(float lo, float hi) {
    unsigned r;
    asm("v_cvt_pk_bf16_f32 %0, %1, %2" : "=v"(r) : "v"(lo), "v"(hi));
    return r;
}

#define GLD_LDS16(g, l) __builtin_amdgcn_global_load_lds( \
    (const __attribute__((address_space(1))) void*)(g),   \
    (__attribute__((address_space(3))) void*)(l), 16, 0, 0)

#define MFMA16(a, b, c) __builtin_amdgcn_mfma_f32_16x16x32_bf16(a, b, c, 0, 0, 0)

// optimizer-level fence: memory ops cannot cross; inserts no waitcnt.
#define LOAD_FENCE() asm volatile("" ::: "memory")

// counted sync: drains the OLDER stage (4 ops), leaves the newest in flight
#define TILE_SYNC() do {                                          \
    asm volatile("s_waitcnt vmcnt(4)" ::: "memory");              \
    __builtin_amdgcn_s_barrier();                                 \
    __builtin_amdgcn_sched_barrier(0);                            \
} while (0)

// full sync: drain all VMEM, barrier, no-hoist
#define TILE_SYNC_FULL() do {                                     \
    asm volatile("s_waitcnt vmcnt(0)" ::: "memory");              \
    __builtin_amdgcn_s_barrier();                                 \
    __builtin_amdgcn_sched_barrier(0);                            \
} while (0)

// ---------------- fused cast: x (4 slices) + 4 weights, one launch ----------------
__global__ __launch_bounds__(256) void cast_all_kernel(
    const float* __restrict__ x,
    const float* __restrict__ w0, const float* __restrict__ w1,
    const float* __restrict__ w2, const float* __restrict__ w3,
    u16* __restrict__ xo,
    u16* __restrict__ o0, u16* __restrict__ o1,
    u16* __restrict__ o2, u16* __restrict__ o3) {
    const int z = blockIdx.y;              // 0..3: x quarters; 4..7: weights
    const int n4 = (DMODEL * DMODEL) / 4;  // 262144 float4 per slice
    const float* in;
    u16* out;
    if (z < 4)      { in = x + (size_t)z * n4 * 4;  out = xo + (size_t)z * n4 * 4; }
    else if (z == 4){ in = w0; out = o0; }
    else if (z == 5){ in = w1; out = o1; }
    else if (z == 6){ in = w2; out = o2; }
    else            { in = w3; out = o3; }
    int i = blockIdx.x * 256 + threadIdx.x;
    if (i < n4) {
        const float4 v = reinterpret_cast<const float4*>(in)[i];
        u16x4 o;
        o.x = f2bf(v.x); o.y = f2bf(v.y); o.z = f2bf(v.z); o.w = f2bf(v.w);
        reinterpret_cast<u16x4*>(out)[i] = o;
    }
}

// ======== shared GEMM machinery: BK=32, 3-deep LDS pipeline, counted vmcnt ========
#define GEMM_STAGE(SRC, SRCLD, KCOL, LDSBASE) do {                            \
    _Pragma("unroll")                                                          \
    for (int _i = 0; _i < 2; ++_i) {                                           \
        const int _s = _i * 256 + tid;                                         \
        const int _row = _s >> 2;                                              \
        const int _u = (_s & 3) ^ ((_row >> 1) & 3);                           \
        GLD_LDS16((SRC) + (size_t)(_row) * (SRCLD) + (KCOL) + _u * 8,          \
                  (LDSBASE) + _s * 8);                                         \
    }                                                                          \
} while (0)

static __device__ __forceinline__ short8 lds_frag(const u16* base, int row, int lg) {
    const int u = lg ^ ((row >> 1) & 3);
    return *(const short8*)(base + row * 32 + u * 8);
}

// ---------------- QKV projection GEMM: C = x @ W^T + b ----------------
__global__ __launch_bounds__(256) void gemm_qkv_kernel(
    const u16* __restrict__ xbf,
    const u16* __restrict__ wqbf, const u16* __restrict__ wkbf, const u16* __restrict__ wvbf,
    const float* __restrict__ bq, const float* __restrict__ bk, const float* __restrict__ bv,
    u16* __restrict__ qout, u16* __restrict__ kout, u16* __restrict__ vtout)
{
    __shared__ u16 As[3][128][32];
    __shared__ u16 Bs[3][128][32];

    const int z = blockIdx.z;
    const u16* __restrict__ W = (z == 0) ? wqbf : (z == 1) ? wkbf : wvbf;
    const float* __restrict__ bias = (z == 0) ? bq : (z == 1) ? bk : bv;

    const int tid  = threadIdx.x;
    const int lane = tid & 63;
    const int wid  = tid >> 6;
    const int wm = (wid >> 1) * 64;
    const int wn = (wid & 1) * 64;
    const int lr = lane & 15;
    const int lg = lane >> 4;

    const int m0 = blockIdx.y * 128;
    const int n0 = blockIdx.x * 128;

    const u16* __restrict__ Abase = xbf + (size_t)m0 * DMODEL;
    const u16* __restrict__ Bbase = W + (size_t)n0 * DMODEL;

    f32x4 acc[4][4] = {};

#define QKV_COMPUTE(BUF)                                                      \
    do {                                                                      \
        short8 af[4], bfr[4];                                                 \
        _Pragma("unroll")                                                     \
        for (int t2 = 0; t2 < 4; ++t2)                                        \
            af[t2] = lds_frag(&As[BUF][0][0], wm + t2 * 16 + lr, lg);         \
        _Pragma("unroll")                                                     \
        for (int t2 = 0; t2 < 4; ++t2)                                        \
            bfr[t2] = lds_frag(&Bs[BUF][0][0], wn + t2 * 16 + lr, lg);        \
        _Pragma("unroll")                                                     \
        for (int mt = 0; mt < 4; ++mt)                                        \
            _Pragma("unroll")                                                 \
            for (int nt = 0; nt < 4; ++nt)                                    \
                acc[mt][nt] = MFMA16(af[mt], bfr[nt], acc[mt][nt]);           \
    } while (0)

    // prologue: two stages in flight, drain only the first
    GEMM_STAGE(Abase, DMODEL, 0, &As[0][0][0]);
    GEMM_STAGE(Bbase, DMODEL, 0, &Bs[0][0][0]);
    GEMM_STAGE(Abase, DMODEL, 32, &As[1][0][0]);
    GEMM_STAGE(Bbase, DMODEL, 32, &Bs[1][0][0]);
    LOAD_FENCE();
    TILE_SYNC();   // vmcnt(4): stage0 done, stage1 in flight

    for (int t = 0; t < 32; ++t) {
        const int cb = t % 3;
        if (t + 2 < 32) {
            const int nb = (t + 2) % 3;
            GEMM_STAGE(Abase, DMODEL, (t + 2) * 32, &As[nb][0][0]);
            GEMM_STAGE(Bbase, DMODEL, (t + 2) * 32, &Bs[nb][0][0]);
            LOAD_FENCE();
            QKV_COMPUTE(cb);
            TILE_SYNC();            // drains stage(t+1); stage(t+2) stays in flight
        } else {
            QKV_COMPUTE(cb);
            TILE_SYNC_FULL();       // tail: no stage issued, drain everything
        }
    }
#undef QKV_COMPUTE

#pragma unroll
    for (int mt = 0; mt < 4; ++mt) {
#pragma unroll
        for (int nt = 0; nt < 4; ++nt) {
            const int n = n0 + wn + nt * 16 + lr;
            const int h = (n >> 6) & (NH - 1);
            const int hd = n & (HD - 1);
            const float bia = bias[n];
#pragma unroll
            for (int r = 0; r < 4; ++r) {
                const int m = m0 + wm + mt * 16 + lg * 4 + r;
                const int bb = m >> 11;
                const int ss = m & (S_LEN - 1);
                const float v = acc[mt][nt][r] + bia;
                const int bh = bb * NH + h;
                if (z == 0) {
                    qout[((size_t)bh * S_LEN + ss) * HD + hd] = f2bf(v * 0.125f);
                } else if (z == 1) {
                    kout[((size_t)bh * S_LEN + ss) * HD + hd] = f2bf(v);
                } else {
                    vtout[((size_t)bh * HD + hd) * S_LEN + ss] = f2bf(v);
                }
            }
        }
    }
}

// ---------------- flash attention (R15/R16 proven body, 3 blocks/CU) ----------------
__global__ __launch_bounds__(256, 3) void attn_kernel(
    const u16* __restrict__ qbf, const u16* __restrict__ kbf,
    const u16* __restrict__ vtbf, const float* __restrict__ rel,
    u16* __restrict__ att)
{
    __shared__ u16 Klds[2][64][64];   // [buf][k][hd]  8KB each
    __shared__ u16 Vlds[2][64][64];   // [buf][hd][k]  8KB each
    __shared__ u16 P[4][16][72];      // per-wave P^T staging (padded)

    const int tid  = threadIdx.x;
    const int lane = tid & 63;
    const int wid  = tid >> 6;
    const int c = lane & 15;
    const int g = lane >> 4;

    const int h = blockIdx.x >> 1;
    const int b = blockIdx.x & 1;
    const int bh = b * NH + h;
    const int blkq = gridDim.y - 1 - blockIdx.y;   // heavy (high-q) blocks first
    const int q0 = blkq * 64;
    const int qv = q0 + wid * 16 + c;

    const size_t base = (size_t)bh * S_LEN * HD;   // also valid base for vtbf

    const short8 qf0 = *(const short8*)&qbf[base + (size_t)qv * HD + g * 8];
    const short8 qf1 = *(const short8*)&qbf[base + (size_t)qv * HD + 32 + g * 8];

    const float* __restrict__ relrow = rel + (size_t)h * S_LEN * S_LEN + (size_t)qv * S_LEN;

    f32x4 o[4] = {};
    float m_run = -3e38f, l_run = 0.f;
    f32x4 rbA[4], rbB[4];

    const int nkt = blkq + 1;

    auto stage = [&](int kt, int bb) {
        const int k0 = kt * 64;
#pragma unroll
        for (int i = 0; i < 2; ++i) {
            const int s = i * 256 + tid;
            const int row = s >> 3;                 // k row
            const int u = (s & 7) ^ (row & 7);      // logical hd-unit
            GLD_LDS16(kbf + base + (size_t)(k0 + row) * HD + u * 8,
                      &Klds[bb][0][0] + s * 8);
        }
#pragma unroll
        for (int i = 0; i < 2; ++i) {
            const int s = i * 256 + tid;
            const int row = s >> 3;                 // hd row
            const int u = (s & 7) ^ (row & 7);      // logical k-unit
            GLD_LDS16(vtbf + base + (size_t)row * S_LEN + k0 + u * 8,
                      &Vlds[bb][0][0] + s * 8);
        }
    };

    auto rel_into = [&](f32x4 (&rb)[4], int kt) {
        const float* rn = relrow + kt * 64;
        rb[0] = *(const f32x4*)&rn[g * 4];
        rb[1] = *(const f32x4*)&rn[16 + g * 4];
        rb[2] = *(const f32x4*)&rn[32 + g * 4];
        rb[3] = *(const f32x4*)&rn[48 + g * 4];
    };

    auto compute_tile = [&](int cur, int k0, bool diag, const f32x4 (&rb)[4]) {
        short8 kf[8];
#pragma unroll
        for (int mt = 0; mt < 4; ++mt) {
            const u16* kp = &Klds[cur][0][0] + (mt * 16 + c) * 64;
            kf[2 * mt]     = *(const short8*)(kp + ((g ^ (c & 7)) * 8));
            kf[2 * mt + 1] = *(const short8*)(kp + (((4 + g) ^ (c & 7)) * 8));
        }
        f32x4 st[4] = {};
        __builtin_amdgcn_s_setprio(1);
#pragma unroll
        for (int mt = 0; mt < 4; ++mt) {
            st[mt] = MFMA16(kf[2 * mt], qf0, st[mt]);
            st[mt] = MFMA16(kf[2 * mt + 1], qf1, st[mt]);
        }
        __builtin_amdgcn_s_setprio(0);

        short8 vf[8];
#pragma unroll
        for (int nt = 0; nt < 4; ++nt) {
            const u16* vp = &Vlds[cur][0][0] + (nt * 16 + c) * 64;
            vf[2 * nt]     = *(const short8*)(vp + ((g ^ (c & 7)) * 8));
            vf[2 * nt + 1] = *(const short8*)(vp + (((4 + g) ^ (c & 7)) * 8));
        }

        float tm = -3e38f;
        if (diag) {
#pragma unroll
            for (int mt = 0; mt < 4; ++mt)
#pragma unroll
                for (int r = 0; r < 4; ++r) {
                    const int k = k0 + mt * 16 + g * 4 + r;
                    float sv = st[mt][r] + rb[mt][r];
                    if (k > qv) sv = -1e30f;
                    st[mt][r] = sv;
                    tm = fmaxf(tm, sv);
                }
        } else {
#pragma unroll
            for (int mt = 0; mt < 4; ++mt)
#pragma unroll
                for (int r = 0; r < 4; ++r) {
                    const float sv = st[mt][r] + rb[mt][r];
                    st[mt][r] = sv;
                    tm = fmaxf(tm, sv);
                }
        }

        if (!__all(tm <= m_run + 8.0f)) {
            tm = fmaxf(tm, __shfl_xor(tm, 16));
            tm = fmaxf(tm, __shfl_xor(tm, 32));
            const float mn = fmaxf(m_run, tm);
            const float sc = __expf(m_run - mn);
            m_run = mn;
            l_run *= sc;
#pragma unroll
            for (int r = 0; r < 4; ++r) {
                const float scq = __shfl(sc, g * 4 + r);
#pragma unroll
                for (int nt = 0; nt < 4; ++nt) o[nt][r] *= scq;
            }
        }

        float rsum = 0.f;
#pragma unroll
        for (int mt = 0; mt < 4; ++mt)
#pragma unroll
            for (int r = 0; r < 4; ++r) {
                const float e = __expf(st[mt][r] - m_run);
                st[mt][r] = e;
                rsum += e;
            }
        rsum += __shfl_xor(rsum, 16);
        rsum += __shfl_xor(rsum, 32);
        l_run += rsum;

#pragma unroll
        for (int mt = 0; mt < 4; ++mt) {
            uint2 pk;
            pk.x = cvtpk_bf16(st[mt][0], st[mt][1]);
            pk.y = cvtpk_bf16(st[mt][2], st[mt][3]);
            *(uint2*)&P[wid][c][mt * 16 + g * 4] = pk;
        }
        const short8 pa0 = *(const short8*)&P[wid][c][g * 8];
        const short8 pa1 = *(const short8*)&P[wid][c][32 + g * 8];

        __builtin_amdgcn_s_setprio(1);
        o[0] = MFMA16(pa0, vf[0], o[0]);
        o[0] = MFMA16(pa1, vf[1], o[0]);
        o[1] = MFMA16(pa0, vf[2], o[1]);
        o[1] = MFMA16(pa1, vf[3], o[1]);
        o[2] = MFMA16(pa0, vf[4], o[2]);
        o[2] = MFMA16(pa1, vf[5], o[2]);
        o[3] = MFMA16(pa0, vf[6], o[3]);
        o[3] = MFMA16(pa1, vf[7], o[3]);
        __builtin_amdgcn_s_setprio(0);
    };

    // prologue: stage tile 0, rel(0)->rbA, rel(1)->rbB; full drain + barrier
    stage(0, 0);
    LOAD_FENCE();
    rel_into(rbA, 0);
    if (nkt > 1) rel_into(rbB, 1);
    __syncthreads();

    // Invariant at top of even-tile body: rbA = rel(t), rbB = rel(t+1).
    int cur = 0;
    int t = 0;
    while (t + 1 < nkt - 1) {
        stage(t + 1, cur ^ 1);
        LOAD_FENCE();
        compute_tile(cur, t * 64, false, rbA);
        rel_into(rbA, t + 2);
        LOAD_FENCE();
        TILE_SYNC();
        cur ^= 1;

        stage(t + 2, cur ^ 1);
        LOAD_FENCE();
        compute_tile(cur, (t + 1) * 64, false, rbB);
        if (t + 3 < nkt) {
            rel_into(rbB, t + 3);
            LOAD_FENCE();
            TILE_SYNC();
        } else {
            LOAD_FENCE();
            TILE_SYNC_FULL();
        }
        cur ^= 1;

        t += 2;
    }

    if (t < nkt - 1) {
        stage(t + 1, cur ^ 1);
        LOAD_FENCE();
        compute_tile(cur, t * 64, false, rbA);
        TILE_SYNC_FULL();
        cur ^= 1;
        compute_tile(cur, (nkt - 1) * 64, true, rbB);
    } else {
        compute_tile(cur, (nkt - 1) * 64, true, rbA);
    }

    // direct epilogue: normalize and store
#pragma unroll
    for (int r = 0; r < 4; ++r) {
        const float linv = 1.0f / __shfl(l_run, g * 4 + r);
        const int q = q0 + wid * 16 + g * 4 + r;
#pragma unroll
        for (int nt = 0; nt < 4; ++nt) {
            att[((size_t)(b * S_LEN + q)) * DMODEL + h * HD + nt * 16 + c] =
                f2bf(o[nt][r] * linv);
        }
    }
}

// ---------------- O projection GEMM + bias + residual (bf16 y, bf16 residual) ----------------
__global__ __launch_bounds__(256) void gemm_o_kernel(
    const u16* __restrict__ att, const u16* __restrict__ wobf,
    const float* __restrict__ bo, const u16* __restrict__ xbf,
    u16* __restrict__ y)
{
    __shared__ u16 As[3][128][32];
    __shared__ u16 Bs[3][128][32];

    const int tid  = threadIdx.x;
    const int lane = tid & 63;
    const int wid  = tid >> 6;
    const int wm = (wid >> 1) * 64;
    const int wn = (wid & 1) * 64;
    const int lr = lane & 15;
    const int lg = lane >> 4;

    const int m0 = blockIdx.y * 128;
    const int n0 = blockIdx.x * 128;

    const u16* __restrict__ Abase = att + (size_t)m0 * DMODEL;
    const u16* __restrict__ Bbase = wobf + (size_t)n0 * DMODEL;

    f32x4 acc[4][4] = {};

#define O_COMPUTE(BUF)                                                        \
    do {                                                                      \
        short8 af[4], bfr[4];                                                 \
        _Pragma("unroll")                                                     \
        for (int t2 = 0; t2 < 4; ++t2)                                        \
            af[t2] = lds_frag(&As[BUF][0][0], wm + t2 * 16 + lr, lg);         \
        _Pragma("unroll")                                                     \
        for (int t2 = 0; t2 < 4; ++t2)                                        \
            bfr[t2] = lds_frag(&Bs[BUF][0][0], wn + t2 * 16 + lr, lg);        \
        _Pragma("unroll")                                                     \
        for (int mt = 0; mt < 4; ++mt)                                        \
            _Pragma("unroll")                                                 \
            for (int nt = 0; nt < 4; ++nt)                                    \
                acc[mt][nt] = MFMA16(af[mt], bfr[nt], acc[mt][nt]);           \
    } while (0)

    GEMM_STAGE(Abase, DMODEL, 0, &As[0][0][0]);
    GEMM_STAGE(Bbase, DMODEL, 0, &Bs[0][0][0]);
    GEMM_STAGE(Abase, DMODEL, 32, &As[1][0][0]);
    GEMM_STAGE(Bbase, DMODEL, 32, &Bs[1][0][0]);
    LOAD_FENCE();
    TILE_SYNC();   // vmcnt(4): stage0 done, stage1 in flight

    for (int t = 0; t < 32; ++t) {
        const int cb = t % 3;
        if (t + 2 < 32) {
            const int nb = (t + 2) % 3;
            GEMM_STAGE(Abase, DMODEL, (t + 2) * 32, &As[nb][0][0]);
            GEMM_STAGE(Bbase, DMODEL, (t + 2) * 32, &Bs[nb][0][0]);
            LOAD_FENCE();
            O_COMPUTE(cb);
            TILE_SYNC();
        } else {
            O_COMPUTE(cb);
            TILE_SYNC_FULL();
        }
    }
#undef O_COMPUTE

#pragma unroll
    for (int mt = 0; mt < 4; ++mt) {
#pragma unroll
        for (int nt = 0; nt < 4; ++nt) {
            const int n = n0 + wn + nt * 16 + lr;
            const float bia = bo[n];
#pragma unroll
            for (int r = 0; r < 4; ++r) {
                const int m = m0 + wm + mt * 16 + lg * 4 + r;
                const size_t idx = (size_t)m * DMODEL + n;
                y[idx] = f2bf(acc[mt][nt][r] + bia + bf2f(xbf[idx]));
            }
        }
    }
}

// ---------------- LayerNorm (bf16 input) ----------------
__global__ __launch_bounds__(256) void ln_kernel(
    const u16* __restrict__ y, const float* __restrict__ gamma,
    const float* __restrict__ beta, float* __restrict__ out)
{
    __shared__ float red[8];
    const int row = blockIdx.x;
    const int tid = threadIdx.x;
    const size_t base = (size_t)row * DMODEL + tid * 4;
    const u16x4 vb = *(const u16x4*)&y[base];
    float v0 = bf2f(vb.x), v1 = bf2f(vb.y), v2 = bf2f(vb.z), v3 = bf2f(vb.w);
    float s  = v0 + v1 + v2 + v3;
    float ss = v0 * v0 + v1 * v1 + v2 * v2 + v3 * v3;
#pragma unroll
    for (int off = 1; off < 64; off <<= 1) {
        s  += __shfl_xor(s, off);
        ss += __shfl_xor(ss, off);
    }
    const int w = tid >> 6;
    if ((tid & 63) == 0) { red[w] = s; red[4 + w] = ss; }
    __syncthreads();
    s  = red[0] + red[1] + red[2] + red[3];
    ss = red[4] + red[5] + red[6] + red[7];
    const float mu = s * (1.0f / DMODEL);
    const float var = ss * (1.0f / DMODEL) - mu * mu;
    const float rstd = rsqrtf(var + 1e-5f);
    const int col = tid * 4;
    float4 o;
    o.x = (v0 - mu) * rstd * gamma[col + 0] + beta[col + 0];
    o.y = (v1 - mu) * rstd * gamma[col + 1] + beta[col + 1];
    o.z = (v2 - mu) * rstd * gamma[col + 2] + beta[col + 2];
    o.w = (v3 - mu) * rstd * gamma[col + 3] + beta[col + 3];
    *(float4*)&out[base] = o;
}

extern "C" void kernel_launch(void* const* d_in, const int* in_sizes, int n_in,
                              void* d_out, int out_size, void* d_ws, size_t ws_size,
                              hipStream_t stream) {
    (void)in_sizes; (void)n_in; (void)out_size; (void)ws_size;
    const float* x     = (const float*)d_in[0];
    const float* Wq    = (const float*)d_in[1];
    const float* bq    = (const float*)d_in[2];
    const float* Wk    = (const float*)d_in[3];
    const float* bk    = (const float*)d_in[4];
    const float* Wv    = (const float*)d_in[5];
    const float* bv    = (const float*)d_in[6];
    const float* Wo    = (const float*)d_in[7];
    const float* bo    = (const float*)d_in[8];
    const float* rel   = (const float*)d_in[9];
    const float* gamma = (const float*)d_in[10];
    const float* beta  = (const float*)d_in[11];
    float* out = (float*)d_out;

    char* ws = (char*)d_ws;
    u16* xbf   = (u16*)(ws);                     //  8 MB
    u16* wqbf  = (u16*)(ws + ( 8u << 20));       //  2 MB
    u16* wkbf  = (u16*)(ws + (10u << 20));       //  2 MB
    u16* wvbf  = (u16*)(ws + (12u << 20));       //  2 MB
    u16* wobf  = (u16*)(ws + (14u << 20));       //  2 MB
    u16* qbf   = (u16*)(ws + (16u << 20));       //  8 MB (B,H,S,HD)
    u16* kbf   = (u16*)(ws + (24u << 20));       //  8 MB
    u16* vtbf  = (u16*)(ws + (32u << 20));       //  8 MB (B,H,HD,S)
    u16* attbf = (u16*)(ws + (40u << 20));       //  8 MB (B*S, D)
    u16* ybf   = (u16*)(ws + (48u << 20));       //  8 MB (B*S, D) bf16

    cast_all_kernel<<<dim3(1024, 8), 256, 0, stream>>>(
        x, Wq, Wk, Wv, Wo, xbf, wqbf, wkbf, wvbf, wobf);

    gemm_qkv_kernel<<<dim3(8, 32, 3), 256, 0, stream>>>(
        xbf, wqbf, wkbf, wvbf, bq, bk, bv, qbf, kbf, vtbf);

    attn_kernel<<<dim3(2 * NH, 32), 256, 0, stream>>>(qbf, kbf, vtbf, rel, attbf);

    gemm_o_kernel<<<dim3(8, 32), 256, 0, stream>>>(attbf, wobf, bo, xbf, ybf);

    ln_kernel<<<2 * S_LEN, 256, 0, stream>>>(ybf, gamma, beta, out);
}

// Round 22
// 162.425 us; speedup vs baseline: 1.1296x; 1.1296x over previous
//
#include <hip/hip_runtime.h>

typedef __attribute__((ext_vector_type(8))) short short8;
typedef __attribute__((ext_vector_type(4))) float f32x4;
typedef unsigned short u16;
typedef __attribute__((ext_vector_type(4))) unsigned short u16x4;

#define S_LEN 2048
#define DMODEL 1024
#define NH 16
#define HD 64

static __device__ __forceinline__ u16 f2bf(float f) {
    union { float f; unsigned u; } x; x.f = f;
    unsigned r = x.u + 0x7fffu + ((x.u >> 16) & 1u);
    return (u16)(r >> 16);
}

static __device__ __forceinline__ float bf2f(u16 v) {
    union { unsigned u; float f; } x; x.u = ((unsigned)v) << 16;
    return x.f;
}

// pack two f32 -> one u32 of two bf16 (RNE), src0 -> low 16, src1 -> high 16
static __device__ __forceinline__ unsigned cvtpk_bf16(float lo, float hi) {
    unsigned r;
    asm("v_cvt_pk_bf16_f32 %0, %1, %2" : "=v"(r) : "v"(lo), "v"(hi));
    return r;
}

#define GLD_LDS16(g, l) __builtin_amdgcn_global_load_lds( \
    (const __attribute__((address_space(1))) void*)(g),   \
    (__attribute__((address_space(3))) void*)(l), 16, 0, 0)

#define MFMA16(a, b, c) __builtin_amdgcn_mfma_f32_16x16x32_bf16(a, b, c, 0, 0, 0)

// optimizer-level fence: memory ops cannot cross; inserts no waitcnt.
#define LOAD_FENCE() asm volatile("" ::: "memory")

// steady-state sync: drains {prev rel, this stage}, leaves this rel in flight
#define TILE_SYNC() do {                                          \
    asm volatile("s_waitcnt vmcnt(4)" ::: "memory");              \
    __builtin_amdgcn_s_barrier();                                 \
    __builtin_amdgcn_sched_barrier(0);                            \
} while (0)

// full sync: drain all VMEM, barrier, no-hoist
#define TILE_SYNC_FULL() do {                                     \
    asm volatile("s_waitcnt vmcnt(0)" ::: "memory");              \
    __builtin_amdgcn_s_barrier();                                 \
    __builtin_amdgcn_sched_barrier(0);                            \
} while (0)

// ---------------- fused cast: x (4 slices) + 4 weights, one launch ----------------
__global__ __launch_bounds__(256) void cast_all_kernel(
    const float* __restrict__ x,
    const float* __restrict__ w0, const float* __restrict__ w1,
    const float* __restrict__ w2, const float* __restrict__ w3,
    u16* __restrict__ xo,
    u16* __restrict__ o0, u16* __restrict__ o1,
    u16* __restrict__ o2, u16* __restrict__ o3) {
    const int z = blockIdx.y;              // 0..3: x quarters; 4..7: weights
    const int n4 = (DMODEL * DMODEL) / 4;  // 262144 float4 per slice
    const float* in;
    u16* out;
    if (z < 4)      { in = x + (size_t)z * n4 * 4;  out = xo + (size_t)z * n4 * 4; }
    else if (z == 4){ in = w0; out = o0; }
    else if (z == 5){ in = w1; out = o1; }
    else if (z == 6){ in = w2; out = o2; }
    else            { in = w3; out = o3; }
    int i = blockIdx.x * 256 + threadIdx.x;
    if (i < n4) {
        const float4 v = reinterpret_cast<const float4*>(in)[i];
        u16x4 o;
        o.x = f2bf(v.x); o.y = f2bf(v.y); o.z = f2bf(v.z); o.w = f2bf(v.w);
        reinterpret_cast<u16x4*>(out)[i] = o;
    }
}

// ======== shared GEMM machinery: BK=32, LDS dbuf, swizzled, counted sync ========
#define GEMM_STAGE(SRC, SRCLD, KCOL, LDSBASE) do {                            \
    _Pragma("unroll")                                                          \
    for (int _i = 0; _i < 2; ++_i) {                                           \
        const int _s = _i * 256 + tid;                                         \
        const int _row = _s >> 2;                                              \
        const int _u = (_s & 3) ^ ((_row >> 1) & 3);                           \
        GLD_LDS16((SRC) + (size_t)(_row) * (SRCLD) + (KCOL) + _u * 8,          \
                  (LDSBASE) + _s * 8);                                         \
    }                                                                          \
} while (0)

static __device__ __forceinline__ short8 lds_frag(const u16* base, int row, int lg) {
    const int u = lg ^ ((row >> 1) & 3);
    return *(const short8*)(base + row * 32 + u * 8);
}

// ---------------- QKV projection GEMM: C = x @ W^T + b ----------------
__global__ __launch_bounds__(256) void gemm_qkv_kernel(
    const u16* __restrict__ xbf,
    const u16* __restrict__ wqbf, const u16* __restrict__ wkbf, const u16* __restrict__ wvbf,
    const float* __restrict__ bq, const float* __restrict__ bk, const float* __restrict__ bv,
    u16* __restrict__ qout, u16* __restrict__ kout, u16* __restrict__ vtout)
{
    __shared__ u16 As[2][128][32];
    __shared__ u16 Bs[2][128][32];

    const int z = blockIdx.z;
    const u16* __restrict__ W = (z == 0) ? wqbf : (z == 1) ? wkbf : wvbf;
    const float* __restrict__ bias = (z == 0) ? bq : (z == 1) ? bk : bv;

    const int tid  = threadIdx.x;
    const int lane = tid & 63;
    const int wid  = tid >> 6;
    const int wm = (wid >> 1) * 64;
    const int wn = (wid & 1) * 64;
    const int lr = lane & 15;
    const int lg = lane >> 4;

    const int m0 = blockIdx.y * 128;
    const int n0 = blockIdx.x * 128;

    const u16* __restrict__ Abase = xbf + (size_t)m0 * DMODEL;
    const u16* __restrict__ Bbase = W + (size_t)n0 * DMODEL;

    f32x4 acc[4][4] = {};

#define QKV_COMPUTE(BUF)                                                      \
    do {                                                                      \
        short8 af[4], bfr[4];                                                 \
        _Pragma("unroll")                                                     \
        for (int t = 0; t < 4; ++t)                                           \
            af[t] = lds_frag(&As[BUF][0][0], wm + t * 16 + lr, lg);           \
        _Pragma("unroll")                                                     \
        for (int t = 0; t < 4; ++t)                                           \
            bfr[t] = lds_frag(&Bs[BUF][0][0], wn + t * 16 + lr, lg);          \
        _Pragma("unroll")                                                     \
        for (int mt = 0; mt < 4; ++mt)                                        \
            _Pragma("unroll")                                                 \
            for (int nt = 0; nt < 4; ++nt)                                    \
                acc[mt][nt] = MFMA16(af[mt], bfr[nt], acc[mt][nt]);           \
    } while (0)

    GEMM_STAGE(Abase, DMODEL, 0, &As[0][0][0]);
    GEMM_STAGE(Bbase, DMODEL, 0, &Bs[0][0][0]);
    __syncthreads();

    for (int kt = 0; kt < 32; kt += 2) {
        GEMM_STAGE(Abase, DMODEL, (kt + 1) * 32, &As[1][0][0]);
        GEMM_STAGE(Bbase, DMODEL, (kt + 1) * 32, &Bs[1][0][0]);
        LOAD_FENCE();
        QKV_COMPUTE(0);
        TILE_SYNC_FULL();

        if (kt + 2 < 32) {
            GEMM_STAGE(Abase, DMODEL, (kt + 2) * 32, &As[0][0][0]);
            GEMM_STAGE(Bbase, DMODEL, (kt + 2) * 32, &Bs[0][0][0]);
            LOAD_FENCE();
        }
        QKV_COMPUTE(1);
        TILE_SYNC_FULL();
    }
#undef QKV_COMPUTE

#pragma unroll
    for (int mt = 0; mt < 4; ++mt) {
#pragma unroll
        for (int nt = 0; nt < 4; ++nt) {
            const int n = n0 + wn + nt * 16 + lr;
            const int h = (n >> 6) & (NH - 1);
            const int hd = n & (HD - 1);
            const float bia = bias[n];
#pragma unroll
            for (int r = 0; r < 4; ++r) {
                const int m = m0 + wm + mt * 16 + lg * 4 + r;
                const int bb = m >> 11;
                const int ss = m & (S_LEN - 1);
                const float v = acc[mt][nt][r] + bia;
                const int bh = bb * NH + h;
                if (z == 0) {
                    qout[((size_t)bh * S_LEN + ss) * HD + hd] = f2bf(v * 0.125f);
                } else if (z == 1) {
                    kout[((size_t)bh * S_LEN + ss) * HD + hd] = f2bf(v);
                } else {
                    vtout[((size_t)bh * HD + hd) * S_LEN + ss] = f2bf(v);
                }
            }
        }
    }
}

// ---------------- flash attention (R15/R16 proven body, 3 blocks/CU) ----------------
__global__ __launch_bounds__(256, 3) void attn_kernel(
    const u16* __restrict__ qbf, const u16* __restrict__ kbf,
    const u16* __restrict__ vtbf, const float* __restrict__ rel,
    u16* __restrict__ att)
{
    __shared__ u16 Klds[2][64][64];   // [buf][k][hd]  8KB each
    __shared__ u16 Vlds[2][64][64];   // [buf][hd][k]  8KB each
    __shared__ u16 P[4][16][72];      // per-wave P^T staging (padded)

    const int tid  = threadIdx.x;
    const int lane = tid & 63;
    const int wid  = tid >> 6;
    const int c = lane & 15;
    const int g = lane >> 4;

    const int h = blockIdx.x >> 1;
    const int b = blockIdx.x & 1;
    const int bh = b * NH + h;
    const int blkq = gridDim.y - 1 - blockIdx.y;   // heavy (high-q) blocks first
    const int q0 = blkq * 64;
    const int qv = q0 + wid * 16 + c;

    const size_t base = (size_t)bh * S_LEN * HD;   // also valid base for vtbf

    const short8 qf0 = *(const short8*)&qbf[base + (size_t)qv * HD + g * 8];
    const short8 qf1 = *(const short8*)&qbf[base + (size_t)qv * HD + 32 + g * 8];

    const float* __restrict__ relrow = rel + (size_t)h * S_LEN * S_LEN + (size_t)qv * S_LEN;

    f32x4 o[4] = {};
    float m_run = -3e38f, l_run = 0.f;
    f32x4 rbA[4], rbB[4];

    const int nkt = blkq + 1;

    auto stage = [&](int kt, int bb) {
        const int k0 = kt * 64;
#pragma unroll
        for (int i = 0; i < 2; ++i) {
            const int s = i * 256 + tid;
            const int row = s >> 3;                 // k row
            const int u = (s & 7) ^ (row & 7);      // logical hd-unit
            GLD_LDS16(kbf + base + (size_t)(k0 + row) * HD + u * 8,
                      &Klds[bb][0][0] + s * 8);
        }
#pragma unroll
        for (int i = 0; i < 2; ++i) {
            const int s = i * 256 + tid;
            const int row = s >> 3;                 // hd row
            const int u = (s & 7) ^ (row & 7);      // logical k-unit
            GLD_LDS16(vtbf + base + (size_t)row * S_LEN + k0 + u * 8,
                      &Vlds[bb][0][0] + s * 8);
        }
    };

    auto rel_into = [&](f32x4 (&rb)[4], int kt) {
        const float* rn = relrow + kt * 64;
        rb[0] = *(const f32x4*)&rn[g * 4];
        rb[1] = *(const f32x4*)&rn[16 + g * 4];
        rb[2] = *(const f32x4*)&rn[32 + g * 4];
        rb[3] = *(const f32x4*)&rn[48 + g * 4];
    };

    auto compute_tile = [&](int cur, int k0, bool diag, const f32x4 (&rb)[4]) {
        short8 kf[8];
#pragma unroll
        for (int mt = 0; mt < 4; ++mt) {
            const u16* kp = &Klds[cur][0][0] + (mt * 16 + c) * 64;
            kf[2 * mt]     = *(const short8*)(kp + ((g ^ (c & 7)) * 8));
            kf[2 * mt + 1] = *(const short8*)(kp + (((4 + g) ^ (c & 7)) * 8));
        }
        f32x4 st[4] = {};
        __builtin_amdgcn_s_setprio(1);
#pragma unroll
        for (int mt = 0; mt < 4; ++mt) {
            st[mt] = MFMA16(kf[2 * mt], qf0, st[mt]);
            st[mt] = MFMA16(kf[2 * mt + 1], qf1, st[mt]);
        }
        __builtin_amdgcn_s_setprio(0);

        short8 vf[8];
#pragma unroll
        for (int nt = 0; nt < 4; ++nt) {
            const u16* vp = &Vlds[cur][0][0] + (nt * 16 + c) * 64;
            vf[2 * nt]     = *(const short8*)(vp + ((g ^ (c & 7)) * 8));
            vf[2 * nt + 1] = *(const short8*)(vp + (((4 + g) ^ (c & 7)) * 8));
        }

        float tm = -3e38f;
        if (diag) {
#pragma unroll
            for (int mt = 0; mt < 4; ++mt)
#pragma unroll
                for (int r = 0; r < 4; ++r) {
                    const int k = k0 + mt * 16 + g * 4 + r;
                    float sv = st[mt][r] + rb[mt][r];
                    if (k > qv) sv = -1e30f;
                    st[mt][r] = sv;
                    tm = fmaxf(tm, sv);
                }
        } else {
#pragma unroll
            for (int mt = 0; mt < 4; ++mt)
#pragma unroll
                for (int r = 0; r < 4; ++r) {
                    const float sv = st[mt][r] + rb[mt][r];
                    st[mt][r] = sv;
                    tm = fmaxf(tm, sv);
                }
        }

        if (!__all(tm <= m_run + 8.0f)) {
            tm = fmaxf(tm, __shfl_xor(tm, 16));
            tm = fmaxf(tm, __shfl_xor(tm, 32));
            const float mn = fmaxf(m_run, tm);
            const float sc = __expf(m_run - mn);
            m_run = mn;
            l_run *= sc;
#pragma unroll
            for (int r = 0; r < 4; ++r) {
                const float scq = __shfl(sc, g * 4 + r);
#pragma unroll
                for (int nt = 0; nt < 4; ++nt) o[nt][r] *= scq;
            }
        }

        float rsum = 0.f;
#pragma unroll
        for (int mt = 0; mt < 4; ++mt)
#pragma unroll
            for (int r = 0; r < 4; ++r) {
                const float e = __expf(st[mt][r] - m_run);
                st[mt][r] = e;
                rsum += e;
            }
        rsum += __shfl_xor(rsum, 16);
        rsum += __shfl_xor(rsum, 32);
        l_run += rsum;

#pragma unroll
        for (int mt = 0; mt < 4; ++mt) {
            uint2 pk;
            pk.x = cvtpk_bf16(st[mt][0], st[mt][1]);
            pk.y = cvtpk_bf16(st[mt][2], st[mt][3]);
            *(uint2*)&P[wid][c][mt * 16 + g * 4] = pk;
        }
        const short8 pa0 = *(const short8*)&P[wid][c][g * 8];
        const short8 pa1 = *(const short8*)&P[wid][c][32 + g * 8];

        __builtin_amdgcn_s_setprio(1);
        o[0] = MFMA16(pa0, vf[0], o[0]);
        o[0] = MFMA16(pa1, vf[1], o[0]);
        o[1] = MFMA16(pa0, vf[2], o[1]);
        o[1] = MFMA16(pa1, vf[3], o[1]);
        o[2] = MFMA16(pa0, vf[4], o[2]);
        o[2] = MFMA16(pa1, vf[5], o[2]);
        o[3] = MFMA16(pa0, vf[6], o[3]);
        o[3] = MFMA16(pa1, vf[7], o[3]);
        __builtin_amdgcn_s_setprio(0);
    };

    // prologue: stage tile 0, rel(0)->rbA, rel(1)->rbB; full drain + barrier
    stage(0, 0);
    LOAD_FENCE();
    rel_into(rbA, 0);
    if (nkt > 1) rel_into(rbB, 1);
    __syncthreads();

    // Invariant at top of even-tile body: rbA = rel(t), rbB = rel(t+1).
    int cur = 0;
    int t = 0;
    while (t + 1 < nkt - 1) {
        stage(t + 1, cur ^ 1);
        LOAD_FENCE();
        compute_tile(cur, t * 64, false, rbA);
        rel_into(rbA, t + 2);
        LOAD_FENCE();
        TILE_SYNC();
        cur ^= 1;

        stage(t + 2, cur ^ 1);
        LOAD_FENCE();
        compute_tile(cur, (t + 1) * 64, false, rbB);
        if (t + 3 < nkt) {
            rel_into(rbB, t + 3);
            LOAD_FENCE();
            TILE_SYNC();
        } else {
            LOAD_FENCE();
            TILE_SYNC_FULL();
        }
        cur ^= 1;

        t += 2;
    }

    if (t < nkt - 1) {
        stage(t + 1, cur ^ 1);
        LOAD_FENCE();
        compute_tile(cur, t * 64, false, rbA);
        TILE_SYNC_FULL();
        cur ^= 1;
        compute_tile(cur, (nkt - 1) * 64, true, rbB);
    } else {
        compute_tile(cur, (nkt - 1) * 64, true, rbA);
    }

    // direct epilogue: normalize and store
#pragma unroll
    for (int r = 0; r < 4; ++r) {
        const float linv = 1.0f / __shfl(l_run, g * 4 + r);
        const int q = q0 + wid * 16 + g * 4 + r;
#pragma unroll
        for (int nt = 0; nt < 4; ++nt) {
            att[((size_t)(b * S_LEN + q)) * DMODEL + h * HD + nt * 16 + c] =
                f2bf(o[nt][r] * linv);
        }
    }
}

// ---------------- O projection GEMM + bias + residual (bf16 y, bf16 residual) ----------------
__global__ __launch_bounds__(256) void gemm_o_kernel(
    const u16* __restrict__ att, const u16* __restrict__ wobf,
    const float* __restrict__ bo, const u16* __restrict__ xbf,
    u16* __restrict__ y)
{
    __shared__ u16 As[2][128][32];
    __shared__ u16 Bs[2][128][32];

    const int tid  = threadIdx.x;
    const int lane = tid & 63;
    const int wid  = tid >> 6;
    const int wm = (wid >> 1) * 64;
    const int wn = (wid & 1) * 64;
    const int lr = lane & 15;
    const int lg = lane >> 4;

    const int m0 = blockIdx.y * 128;
    const int n0 = blockIdx.x * 128;

    const u16* __restrict__ Abase = att + (size_t)m0 * DMODEL;
    const u16* __restrict__ Bbase = wobf + (size_t)n0 * DMODEL;

    f32x4 acc[4][4] = {};

#define O_COMPUTE(BUF)                                                        \
    do {                                                                      \
        short8 af[4], bfr[4];                                                 \
        _Pragma("unroll")                                                     \
        for (int t = 0; t < 4; ++t)                                           \
            af[t] = lds_frag(&As[BUF][0][0], wm + t * 16 + lr, lg);           \
        _Pragma("unroll")                                                     \
        for (int t = 0; t < 4; ++t)                                           \
            bfr[t] = lds_frag(&Bs[BUF][0][0], wn + t * 16 + lr, lg);          \
        _Pragma("unroll")                                                     \
        for (int mt = 0; mt < 4; ++mt)                                        \
            _Pragma("unroll")                                                 \
            for (int nt = 0; nt < 4; ++nt)                                    \
                acc[mt][nt] = MFMA16(af[mt], bfr[nt], acc[mt][nt]);           \
    } while (0)

    GEMM_STAGE(Abase, DMODEL, 0, &As[0][0][0]);
    GEMM_STAGE(Bbase, DMODEL, 0, &Bs[0][0][0]);
    __syncthreads();

    for (int kt = 0; kt < 32; kt += 2) {
        GEMM_STAGE(Abase, DMODEL, (kt + 1) * 32, &As[1][0][0]);
        GEMM_STAGE(Bbase, DMODEL, (kt + 1) * 32, &Bs[1][0][0]);
        LOAD_FENCE();
        O_COMPUTE(0);
        TILE_SYNC_FULL();

        if (kt + 2 < 32) {
            GEMM_STAGE(Abase, DMODEL, (kt + 2) * 32, &As[0][0][0]);
            GEMM_STAGE(Bbase, DMODEL, (kt + 2) * 32, &Bs[0][0][0]);
            LOAD_FENCE();
        }
        O_COMPUTE(1);
        TILE_SYNC_FULL();
    }
#undef O_COMPUTE

#pragma unroll
    for (int mt = 0; mt < 4; ++mt) {
#pragma unroll
        for (int nt = 0; nt < 4; ++nt) {
            const int n = n0 + wn + nt * 16 + lr;
            const float bia = bo[n];
#pragma unroll
            for (int r = 0; r < 4; ++r) {
                const int m = m0 + wm + mt * 16 + lg * 4 + r;
                const size_t idx = (size_t)m * DMODEL + n;
                y[idx] = f2bf(acc[mt][nt][r] + bia + bf2f(xbf[idx]));
            }
        }
    }
}

// ---------------- LayerNorm (bf16 input) ----------------
__global__ __launch_bounds__(256) void ln_kernel(
    const u16* __restrict__ y, const float* __restrict__ gamma,
    const float* __restrict__ beta, float* __restrict__ out)
{
    __shared__ float red[8];
    const int row = blockIdx.x;
    const int tid = threadIdx.x;
    const size_t base = (size_t)row * DMODEL + tid * 4;
    const u16x4 vb = *(const u16x4*)&y[base];
    float v0 = bf2f(vb.x), v1 = bf2f(vb.y), v2 = bf2f(vb.z), v3 = bf2f(vb.w);
    float s  = v0 + v1 + v2 + v3;
    float ss = v0 * v0 + v1 * v1 + v2 * v2 + v3 * v3;
#pragma unroll
    for (int off = 1; off < 64; off <<= 1) {
        s  += __shfl_xor(s, off);
        ss += __shfl_xor(ss, off);
    }
    const int w = tid >> 6;
    if ((tid & 63) == 0) { red[w] = s; red[4 + w] = ss; }
    __syncthreads();
    s  = red[0] + red[1] + red[2] + red[3];
    ss = red[4] + red[5] + red[6] + red[7];
    const float mu = s * (1.0f / DMODEL);
    const float var = ss * (1.0f / DMODEL) - mu * mu;
    const float rstd = rsqrtf(var + 1e-5f);
    const int col = tid * 4;
    float4 o;
    o.x = (v0 - mu) * rstd * gamma[col + 0] + beta[col + 0];
    o.y = (v1 - mu) * rstd * gamma[col + 1] + beta[col + 1];
    o.z = (v2 - mu) * rstd * gamma[col + 2] + beta[col + 2];
    o.w = (v3 - mu) * rstd * gamma[col + 3] + beta[col + 3];
    *(float4*)&out[base] = o;
}

extern "C" void kernel_launch(void* const* d_in, const int* in_sizes, int n_in,
                              void* d_out, int out_size, void* d_ws, size_t ws_size,
                              hipStream_t stream) {
    (void)in_sizes; (void)n_in; (void)out_size; (void)ws_size;
    const float* x     = (const float*)d_in[0];
    const float* Wq    = (const float*)d_in[1];
    const float* bq    = (const float*)d_in[2];
    const float* Wk    = (const float*)d_in[3];
    const float* bk    = (const float*)d_in[4];
    const float* Wv    = (const float*)d_in[5];
    const float* bv    = (const float*)d_in[6];
    const float* Wo    = (const float*)d_in[7];
    const float* bo    = (const float*)d_in[8];
    const float* rel   = (const float*)d_in[9];
    const float* gamma = (const float*)d_in[10];
    const float* beta  = (const float*)d_in[11];
    float* out = (float*)d_out;

    char* ws = (char*)d_ws;
    u16* xbf   = (u16*)(ws);                     //  8 MB
    u16* wqbf  = (u16*)(ws + ( 8u << 20));       //  2 MB
    u16* wkbf  = (u16*)(ws + (10u << 20));       //  2 MB
    u16* wvbf  = (u16*)(ws + (12u << 20));       //  2 MB
    u16* wobf  = (u16*)(ws + (14u << 20));       //  2 MB
    u16* qbf   = (u16*)(ws + (16u << 20));       //  8 MB (B,H,S,HD)
    u16* kbf   = (u16*)(ws + (24u << 20));       //  8 MB
    u16* vtbf  = (u16*)(ws + (32u << 20));       //  8 MB (B,H,HD,S)
    u16* attbf = (u16*)(ws + (40u << 20));       //  8 MB (B*S, D)
    u16* ybf   = (u16*)(ws + (48u << 20));       //  8 MB (B*S, D) bf16

    cast_all_kernel<<<dim3(1024, 8), 256, 0, stream>>>(
        x, Wq, Wk, Wv, Wo, xbf, wqbf, wkbf, wvbf, wobf);

    gemm_qkv_kernel<<<dim3(8, 32, 3), 256, 0, stream>>>(
        xbf, wqbf, wkbf, wvbf, bq, bk, bv, qbf, kbf, vtbf);

    attn_kernel<<<dim3(2 * NH, 32), 256, 0, stream>>>(qbf, kbf, vtbf, rel, attbf);

    gemm_o_kernel<<<dim3(8, 32), 256, 0, stream>>>(attbf, wobf, bo, xbf, ybf);

    ln_kernel<<<2 * S_LEN, 256, 0, stream>>>(ybf, gamma, beta, out);
}